// Round 1
// baseline (145.843 us; speedup 1.0000x reference)
//
#include <hip/hip_runtime.h>
#include <cstdint>

// out[b] = x[b] @ C[b],  C[b] = sum_h Wq[h] M[b,h] Wo[h]
// R11: Gram-matrix restructure.  M[b,h] = Wk[h]^T (x^T x) Wv[h].
//   G = x^T x computed ONCE per batch (4.3 GF total, split-K fp32 atomics)
//   instead of per-head K/V projections (10.7 GF + 8x head-redundant x reads
//   + LDS-transpose/atomic epilogue).  G is symmetric, so G^T reads are
//   row-major reads of G: no transposes in the tail chain.
// Chain: prep -> xtx(G) -> gv(T2=Wk^T G) -> m(M=T2 Wv) -> tail(C) -> out.

#define BDIM 2
#define LDIM 4096
#define DIN 512
#define HDIM 8
#define DK 64
#define DV 64
#define DOUT 512

using bf16_t = __bf16;
typedef __bf16 bf16x8 __attribute__((ext_vector_type(8)));
typedef float floatx4 __attribute__((ext_vector_type(4)));

__device__ __forceinline__ unsigned short f2bf(float f) {
    unsigned int u = __builtin_bit_cast(unsigned int, f);
    u += 0x7FFFu + ((u >> 16) & 1u);
    return (unsigned short)(u >> 16);
}

__device__ __forceinline__ void gld_lds16(const void* g, void* l) {
    __builtin_amdgcn_global_load_lds(
        (const __attribute__((address_space(1))) void*)g,
        (__attribute__((address_space(3))) void*)l, 16, 0, 0);
}

// ---------------- generic TN MFMA GEMM core ----------------
// C[m][n] = sum_k A[m][k] * B[n][k]   (A, B row-major bf16, k contiguous)
// OUT_MODE: 0 = fp32 store, 1 = bf16 store, 2 = fp32 atomicAdd
template <int BM, int BN, int BK, bool TRANS_OUT, int OUT_MODE>
__device__ __forceinline__ void gemm_core(const bf16_t* A, const bf16_t* B,
                                          void* Cp, int K, int lda, int ldb,
                                          int ldc, int tm, int tn) {
    constexpr int WM = BM / 2, WN = BN / 2;
    constexpr int FM = WM / 16, FN = WN / 16;
    constexpr int CPR = BK / 8;
    __shared__ __align__(16) bf16_t As[BM * BK];
    __shared__ __align__(16) bf16_t Bs[BN * BK];
    const int tid = threadIdx.x;
    const int lane = tid & 63;
    const int wr = (tid >> 7) & 1;
    const int wc = (tid >> 6) & 1;

    A += (size_t)tm * lda;
    B += (size_t)tn * ldb;

    floatx4 acc[FM][FN] = {};

    for (int k0 = 0; k0 < K; k0 += BK) {
#pragma unroll
        for (int i = 0; i < (BM * CPR) / 256; ++i) {
            int c = i * 256 + tid;
            int m = c / CPR, kc = c % CPR;
            gld_lds16(A + (size_t)m * lda + k0 + kc * 8, As + c * 8);
        }
#pragma unroll
        for (int i = 0; i < (BN * CPR) / 256; ++i) {
            int c = i * 256 + tid;
            int m = c / CPR, kc = c % CPR;
            gld_lds16(B + (size_t)m * ldb + k0 + kc * 8, Bs + c * 8);
        }
        __syncthreads();

#pragma unroll
        for (int kk = 0; kk < BK; kk += 32) {
            bf16x8 aF[FM], bF[FN];
#pragma unroll
            for (int fm = 0; fm < FM; ++fm)
                aF[fm] = *(const bf16x8*)(As + (wr * WM + fm * 16 + (lane & 15)) * BK +
                                          kk + (lane >> 4) * 8);
#pragma unroll
            for (int fn = 0; fn < FN; ++fn)
                bF[fn] = *(const bf16x8*)(Bs + (wc * WN + fn * 16 + (lane & 15)) * BK +
                                          kk + (lane >> 4) * 8);
#pragma unroll
            for (int fm = 0; fm < FM; ++fm)
#pragma unroll
                for (int fn = 0; fn < FN; ++fn)
                    acc[fm][fn] = __builtin_amdgcn_mfma_f32_16x16x32_bf16(
                        aF[fm], bF[fn], acc[fm][fn], 0, 0, 0);
        }
        __syncthreads();
    }

    const int cr4 = (lane >> 4) * 4;
    const int cn = lane & 15;
#pragma unroll
    for (int fm = 0; fm < FM; ++fm)
#pragma unroll
        for (int fn = 0; fn < FN; ++fn)
#pragma unroll
            for (int r = 0; r < 4; ++r) {
                int m = tm + wr * WM + fm * 16 + cr4 + r;
                int n = tn + wc * WN + fn * 16 + cn;
                size_t idx = TRANS_OUT ? ((size_t)n * ldc + m)
                                       : ((size_t)m * ldc + n);
                if (OUT_MODE == 0)
                    ((float*)Cp)[idx] = acc[fm][fn][r];
                else if (OUT_MODE == 1)
                    ((unsigned short*)Cp)[idx] = f2bf(acc[fm][fn][r]);
                else
                    atomicAdd((float*)Cp + idx, acc[fm][fn][r]);
            }
}

// ---- k_xtx: G[b][i][j] += sum_{l in chunk} xT[b][i][l] * xT[b][j][l]
// tiles 128x64, split-K over L=4096 in 8 chunks of 512 -> 512 blocks.
__global__ __launch_bounds__(256) void k_xtx(const bf16_t* xT, float* G32) {
    const int t = blockIdx.x;          // 0..31 : (mt 0..3) x (nt 0..7)
    const int chunk = blockIdx.y;      // 0..7
    const int b = blockIdx.z;
    const int i0 = (t >> 3) * 128, j0 = (t & 7) * 64;
    const bf16_t* Xb = xT + (size_t)b * DIN * LDIM + (size_t)chunk * 512;
    gemm_core<128, 64, 64, false, 2>(Xb, Xb, G32 + (size_t)b * DIN * DIN, 512,
                                     LDIM, LDIM, DIN, i0, j0);
}

// ---- k_gv: T2[b,h][dk][j] = sum_i WkT[h][dk][i] * G[b][j][i]  (G symmetric)
// A = WkT bf16 (gld_lds), B = G fp32 reg-staged -> bf16 -> LDS.
__global__ __launch_bounds__(256) void k_gv(const bf16_t* WkT, const float* G32,
                                            unsigned short* T2) {
    const int jt = blockIdx.x, h = blockIdx.y, b = blockIdx.z;
    const int j0 = jt * 64;
    __shared__ __align__(16) bf16_t As[64 * 64];
    __shared__ __align__(16) bf16_t Bs[64 * 64];
    const int tid = threadIdx.x;
    const int lane = tid & 63;
    const int wr = (tid >> 7) & 1, wc = (tid >> 6) & 1;
    const int cr4 = (lane >> 4) * 4, cn = lane & 15;

    const bf16_t* A = WkT + (size_t)h * DK * DIN;
    const float* Gb = G32 + (size_t)b * DIN * DIN + (size_t)j0 * DIN;

    floatx4 acc[2][2] = {};
    for (int k0 = 0; k0 < DIN; k0 += 64) {
#pragma unroll
        for (int i = 0; i < 2; ++i) {
            int c = i * 256 + tid, m = c >> 3, kc = c & 7;
            gld_lds16(A + (size_t)m * DIN + k0 + kc * 8, As + c * 8);
        }
#pragma unroll
        for (int i = 0; i < 2; ++i) {
            int c = i * 256 + tid, n = c >> 3, kc = c & 7;
            const float* src = Gb + (size_t)n * DIN + k0 + kc * 8;
            float4 v0 = *(const float4*)src;
            float4 v1 = *(const float4*)(src + 4);
            unsigned short o[8] = {f2bf(v0.x), f2bf(v0.y), f2bf(v0.z), f2bf(v0.w),
                                   f2bf(v1.x), f2bf(v1.y), f2bf(v1.z), f2bf(v1.w)};
            *(uint4*)((unsigned short*)Bs + (size_t)c * 8) = *(const uint4*)o;
        }
        __syncthreads();
#pragma unroll
        for (int kk = 0; kk < 64; kk += 32) {
            bf16x8 aF[2], bF[2];
#pragma unroll
            for (int f = 0; f < 2; ++f) {
                aF[f] = *(const bf16x8*)(As + (wr * 32 + f * 16 + cn) * 64 + kk +
                                         (lane >> 4) * 8);
                bF[f] = *(const bf16x8*)(Bs + (wc * 32 + f * 16 + cn) * 64 + kk +
                                         (lane >> 4) * 8);
            }
#pragma unroll
            for (int fm = 0; fm < 2; ++fm)
#pragma unroll
                for (int fn = 0; fn < 2; ++fn)
                    acc[fm][fn] = __builtin_amdgcn_mfma_f32_16x16x32_bf16(
                        aF[fm], bF[fn], acc[fm][fn], 0, 0, 0);
        }
        __syncthreads();
    }

    unsigned short* dst = T2 + (size_t)(b * HDIM + h) * DK * DIN;
#pragma unroll
    for (int fm = 0; fm < 2; ++fm)
#pragma unroll
        for (int fn = 0; fn < 2; ++fn)
#pragma unroll
            for (int r = 0; r < 4; ++r) {
                int m = wr * 32 + fm * 16 + cr4 + r;   // dk
                int n = wc * 32 + fn * 16 + cn;        // j local
                dst[(size_t)m * DIN + j0 + n] = f2bf(acc[fm][fn][r]);
            }
}

// ---- k_m: M32[b,h][dk][v] = sum_j T2[b,h][dk][j] * WvT[h][v][j]
__global__ __launch_bounds__(256) void k_m(const bf16_t* T2, const bf16_t* WvT,
                                           float* M32) {
    const int h = blockIdx.x, b = blockIdx.y;
    gemm_core<64, 64, 64, false, 0>(T2 + (size_t)(b * HDIM + h) * DK * DIN,
                                    WvT + (size_t)h * DV * DIN,
                                    M32 + (size_t)(b * HDIM + h) * (DK * DV),
                                    DIN, DIN, DIN, DV, 0, 0);
}

// ---- k_tail: CT[b][o][i] = sum_h sum_dk PT[h][o][dk] * Wq[h][i][dk]
//      where PT[h][o][dk] = sum_v WoT[h][o][v] * M[b,h][dk][v]
__global__ __launch_bounds__(256) void k_tail(const bf16_t* WqC, const bf16_t* WoT,
                                              const float* M32, unsigned short* CT) {
    int i0 = blockIdx.x * 64, o0 = blockIdx.y * 64, b = blockIdx.z;
    __shared__ __align__(16) bf16_t Aq[64 * 64];
    __shared__ __align__(16) bf16_t Ws[64 * 64];
    __shared__ __align__(16) bf16_t Msh[64 * 64];
    __shared__ __align__(16) bf16_t PTs[64 * 64];
    const int tid = threadIdx.x;
    const int lane = tid & 63;
    const int wr = (tid >> 7) & 1, wc = (tid >> 6) & 1;
    const int cr4 = (lane >> 4) * 4, cn = lane & 15;

    floatx4 acc[2][2] = {};

    for (int h = 0; h < HDIM; ++h) {
#pragma unroll
        for (int i = 0; i < 2; ++i) {
            int c = i * 256 + tid, m = c >> 3, kc = c & 7;
            gld_lds16(WqC + (size_t)(i0 + m) * DIN + h * 64 + kc * 8, Aq + c * 8);
            gld_lds16(WoT + ((size_t)h * DOUT + o0 + m) * DV + kc * 8, Ws + c * 8);
        }
        const float* Mh = M32 + ((size_t)(b * HDIM + h)) * (DK * DV);
#pragma unroll
        for (int i = 0; i < 4; ++i) {
            int idx = (i * 256 + tid) * 4;
            float4 v = *(const float4*)(Mh + idx);
            *(ushort4*)((unsigned short*)Msh + idx) =
                make_ushort4(f2bf(v.x), f2bf(v.y), f2bf(v.z), f2bf(v.w));
        }
        __syncthreads();

        floatx4 pt[2][2] = {};
#pragma unroll
        for (int kk = 0; kk < 64; kk += 32) {
            bf16x8 aF[2], bF[2];
#pragma unroll
            for (int f = 0; f < 2; ++f) {
                aF[f] = *(const bf16x8*)(Ws + (wr * 32 + f * 16 + cn) * 64 + kk +
                                         (lane >> 4) * 8);
                bF[f] = *(const bf16x8*)(Msh + (wc * 32 + f * 16 + cn) * 64 + kk +
                                         (lane >> 4) * 8);
            }
#pragma unroll
            for (int fm = 0; fm < 2; ++fm)
#pragma unroll
                for (int fn = 0; fn < 2; ++fn)
                    pt[fm][fn] = __builtin_amdgcn_mfma_f32_16x16x32_bf16(
                        aF[fm], bF[fn], pt[fm][fn], 0, 0, 0);
        }
#pragma unroll
        for (int fm = 0; fm < 2; ++fm)
#pragma unroll
            for (int fn = 0; fn < 2; ++fn)
#pragma unroll
                for (int r = 0; r < 4; ++r) {
                    int m = wr * 32 + fm * 16 + cr4 + r;
                    int n = wc * 32 + fn * 16 + cn;
                    ((unsigned short*)PTs)[m * 64 + n] = f2bf(pt[fm][fn][r]);
                }
        __syncthreads();

#pragma unroll
        for (int kk = 0; kk < 64; kk += 32) {
            bf16x8 aF[2], bF[2];
#pragma unroll
            for (int f = 0; f < 2; ++f) {
                aF[f] = *(const bf16x8*)(PTs + (wr * 32 + f * 16 + cn) * 64 + kk +
                                         (lane >> 4) * 8);
                bF[f] = *(const bf16x8*)(Aq + (wc * 32 + f * 16 + cn) * 64 + kk +
                                         (lane >> 4) * 8);
            }
#pragma unroll
            for (int fm = 0; fm < 2; ++fm)
#pragma unroll
                for (int fn = 0; fn < 2; ++fn)
                    acc[fm][fn] = __builtin_amdgcn_mfma_f32_16x16x32_bf16(
                        aF[fm], bF[fn], acc[fm][fn], 0, 0, 0);
        }
        __syncthreads();
    }

    unsigned short* CTb = CT + (size_t)b * DIN * DOUT;
#pragma unroll
    for (int fm = 0; fm < 2; ++fm)
#pragma unroll
        for (int fn = 0; fn < 2; ++fn)
#pragma unroll
            for (int r = 0; r < 4; ++r) {
                int m = wr * 32 + fm * 16 + cr4 + r;
                int n = wc * 32 + fn * 16 + cn;
                CTb[(size_t)(o0 + m) * DIN + i0 + n] = f2bf(acc[fm][fn][r]);
            }
}

// ---- out[b] = x16[b] @ C[b], fp32 out, 64x128 tiles ----
__global__ __launch_bounds__(256) void k_out(const bf16_t* x16, const bf16_t* CT,
                                             float* out) {
    int b = blockIdx.z;
    gemm_core<64, 128, 64, false, 0>(x16 + (size_t)b * LDIM * DIN,
                                     CT + (size_t)b * DIN * DOUT,
                                     out + (size_t)b * LDIM * DOUT, DIN, DIN,
                                     DIN, DOUT, blockIdx.x * 64,
                                     blockIdx.y * 128);
}

// ---------------- prep: x convert (row + transposed), weights, zero G ----
// bids: [0,2048) x->xb16 | [2048,3072) x->xT16 | [3072,3328) weights |
//       [3328,3392) zero G32
__global__ __launch_bounds__(256) void k_prep3(
    const float* x, const float* Wq, const float* Wk, const float* Wv,
    const float* Wo, unsigned short* xb, unsigned short* xT,
    unsigned short* WqC, unsigned short* WkT, unsigned short* WvT,
    unsigned short* WoT, float* G32) {
    __shared__ unsigned short T[64][65];
    int tr = threadIdx.x >> 4, tc4 = (threadIdx.x & 15) * 4;
    int bid = blockIdx.x;
    if (bid < 2048) {
        size_t base = ((size_t)bid * 256 + threadIdx.x) * 8;
        float4 v0 = *(const float4*)(x + base);
        float4 v1 = *(const float4*)(x + base + 4);
        unsigned short o[8] = {f2bf(v0.x), f2bf(v0.y), f2bf(v0.z), f2bf(v0.w),
                               f2bf(v1.x), f2bf(v1.y), f2bf(v1.z), f2bf(v1.w)};
        *(uint4*)(xb + base) = *(const uint4*)o;
        return;
    }
    if (bid < 3072) {  // x -> xT (bf16), 64x64 tiles through LDS
        int p_ = bid - 2048;
        int b = p_ >> 9;
        int q = p_ & 511;
        int lt = q >> 3, it = q & 7;
        const float* src = x + (size_t)b * LDIM * DIN + (size_t)lt * 64 * DIN +
                           (size_t)it * 64;
        unsigned short* dst = xT + (size_t)b * DIN * LDIM +
                              (size_t)it * 64 * LDIM + (size_t)lt * 64;
#pragma unroll
        for (int p = 0; p < 4; ++p) {
            int r = p * 16 + tr;
            float4 v = *(const float4*)(src + (size_t)r * DIN + tc4);
            T[r][tc4 + 0] = f2bf(v.x); T[r][tc4 + 1] = f2bf(v.y);
            T[r][tc4 + 2] = f2bf(v.z); T[r][tc4 + 3] = f2bf(v.w);
        }
        __syncthreads();
#pragma unroll
        for (int p = 0; p < 4; ++p) {
            int c = p * 16 + tr;
            ushort4 u = make_ushort4(T[tc4 + 0][c], T[tc4 + 1][c], T[tc4 + 2][c],
                                     T[tc4 + 3][c]);
            *(ushort4*)(dst + (size_t)c * LDIM + tc4) = u;
        }
        return;
    }
    if (bid >= 3328) {  // zero G32 (2 x 512 x 512 fp32)
        size_t g = ((size_t)(bid - 3328) * 256 + threadIdx.x) * 32;
        float4 z4 = make_float4(0.f, 0.f, 0.f, 0.f);
#pragma unroll
        for (int q = 0; q < 8; ++q) *(float4*)(G32 + g + q * 4) = z4;
        return;
    }
    int p_ = bid - 3072;
    int t = p_ & 7, job = (p_ >> 3) & 3, h = p_ >> 5;
    if (job == 0) {  // Wq[h] -> WqC (i-major, head-interleaved columns)
        const float* src = Wq + (size_t)h * DIN * DK;
#pragma unroll
        for (int p = 0; p < 4; ++p) {
            int i = t * 64 + p * 16 + tr;
            float4 v = *(const float4*)(src + (size_t)i * DK + tc4);
            *(ushort4*)(WqC + (size_t)i * (HDIM * DK) + h * DK + tc4) =
                make_ushort4(f2bf(v.x), f2bf(v.y), f2bf(v.z), f2bf(v.w));
        }
        return;
    }
    const float* src;
    unsigned short* dst;
    int rows, cols, r0, c0;
    if (job == 1) {  // Wk[h] (512x64) -> WkT[h] (64x512)
        src = Wk + (size_t)h * DIN * DK;
        dst = WkT + (size_t)h * DK * DIN;
        rows = DIN; cols = DK; r0 = t * 64; c0 = 0;
    } else if (job == 2) {  // Wv[h] (512x64) -> WvT[h] (64x512)
        src = Wv + (size_t)h * DIN * DV;
        dst = WvT + (size_t)h * DV * DIN;
        rows = DIN; cols = DV; r0 = t * 64; c0 = 0;
    } else {  // Wo[h] (64x512) -> WoT[h] (512x64)
        src = Wo + (size_t)h * DV * DOUT;
        dst = WoT + (size_t)h * DOUT * DV;
        rows = DV; cols = DOUT; r0 = 0; c0 = t * 64;
    }
#pragma unroll
    for (int p = 0; p < 4; ++p) {
        int r = p * 16 + tr;
        float4 v = *(const float4*)(src + (size_t)(r0 + r) * cols + c0 + tc4);
        T[r][tc4 + 0] = f2bf(v.x); T[r][tc4 + 1] = f2bf(v.y);
        T[r][tc4 + 2] = f2bf(v.z); T[r][tc4 + 3] = f2bf(v.w);
    }
    __syncthreads();
#pragma unroll
    for (int p = 0; p < 4; ++p) {
        int c = p * 16 + tr;
        ushort4 u = make_ushort4(T[tc4 + 0][c], T[tc4 + 1][c], T[tc4 + 2][c],
                                 T[tc4 + 3][c]);
        *(ushort4*)(dst + (size_t)(c0 + c) * rows + r0 + tc4) = u;
    }
}

extern "C" void kernel_launch(void* const* d_in, const int* in_sizes, int n_in,
                              void* d_out, int out_size, void* d_ws, size_t ws_size,
                              hipStream_t stream) {
    const float* x  = (const float*)d_in[0];
    const float* Wq = (const float*)d_in[1];
    const float* Wk = (const float*)d_in[2];
    const float* Wv = (const float*)d_in[3];
    const float* Wo = (const float*)d_in[4];
    float* out = (float*)d_out;

    unsigned short* w = (unsigned short*)d_ws;
    unsigned short* xb16 = w; w += (size_t)BDIM * LDIM * DIN;   // 8.4 MB
    unsigned short* xT16 = w; w += (size_t)BDIM * DIN * LDIM;   // 8.4 MB
    unsigned short* WqC  = w; w += (size_t)DIN * HDIM * DK;
    unsigned short* WkT  = w; w += (size_t)HDIM * DK * DIN;
    unsigned short* WvT  = w; w += (size_t)HDIM * DV * DIN;
    unsigned short* WoT  = w; w += (size_t)HDIM * DOUT * DV;
    unsigned short* CT   = w; w += (size_t)BDIM * DIN * DOUT;
    unsigned short* T2   = w; w += (size_t)BDIM * HDIM * DK * DIN;
    float* G32 = (float*)(((uintptr_t)w + 255) & ~(uintptr_t)255);  // 2x512x512
    float* M32 = G32 + (size_t)BDIM * DIN * DIN;                    // 2x8x64x64

    k_prep3<<<dim3(3392), 256, 0, stream>>>(x, Wq, Wk, Wv, Wo, xb16, xT16,
                                            WqC, WkT, WvT, WoT, G32);
    k_xtx<<<dim3(32, 8, BDIM), 256, 0, stream>>>((const bf16_t*)xT16, G32);
    k_gv<<<dim3(8, HDIM, BDIM), 256, 0, stream>>>((const bf16_t*)WkT, G32, T2);
    k_m<<<dim3(HDIM, BDIM), 256, 0, stream>>>((const bf16_t*)T2,
                                              (const bf16_t*)WvT, M32);
    k_tail<<<dim3(8, 8, BDIM), 256, 0, stream>>>((const bf16_t*)WqC,
                                                 (const bf16_t*)WoT, M32, CT);
    k_out<<<dim3(LDIM / 64, DOUT / 128, BDIM), 256, 0, stream>>>(
        (const bf16_t*)xb16, (const bf16_t*)CT, out);
}

// Round 2
// 135.548 us; speedup vs baseline: 1.0759x; 1.0759x over previous
//
#include <hip/hip_runtime.h>
#include <cstdint>

// out[b] = x[b] @ C[b],  C[b] = sum_h Wq[h] M[b,h] Wo[h]
// R12: Gram restructure, execution fixed vs R11.
//   G = x^T x via split-K=4 into PRIVATE per-chunk partials (no atomics,
//   no zero-init).  k_gvm fuses T2 = Wk^T G and M += T2 Wv per j-tile
//   (sums the 4 G partials during staging).  Prep fuses x->xb16 and
//   x->xT16 into one pass over x.  5 launches, no tiny latency-orphan
//   kernels except gvm/tail (128 blocks each).
// Chain: prep -> xtx(Gp[4]) -> gvm(M) -> tail(CT) -> out.

#define BDIM 2
#define LDIM 4096
#define DIN 512
#define HDIM 8
#define DK 64
#define DV 64
#define DOUT 512
#define NCHUNK 4

using bf16_t = __bf16;
typedef __bf16 bf16x8 __attribute__((ext_vector_type(8)));
typedef float floatx4 __attribute__((ext_vector_type(4)));

__device__ __forceinline__ unsigned short f2bf(float f) {
    unsigned int u = __builtin_bit_cast(unsigned int, f);
    u += 0x7FFFu + ((u >> 16) & 1u);
    return (unsigned short)(u >> 16);
}

__device__ __forceinline__ void gld_lds16(const void* g, void* l) {
    __builtin_amdgcn_global_load_lds(
        (const __attribute__((address_space(1))) void*)g,
        (__attribute__((address_space(3))) void*)l, 16, 0, 0);
}

// ---------------- generic TN MFMA GEMM core ----------------
// C[m][n] = sum_k A[m][k] * B[n][k]   (A, B row-major bf16, k contiguous)
// OUT_MODE: 0 = fp32 store, 1 = bf16 store
template <int BM, int BN, int BK, bool TRANS_OUT, int OUT_MODE>
__device__ __forceinline__ void gemm_core(const bf16_t* A, const bf16_t* B,
                                          void* Cp, int K, int lda, int ldb,
                                          int ldc, int tm, int tn) {
    constexpr int WM = BM / 2, WN = BN / 2;
    constexpr int FM = WM / 16, FN = WN / 16;
    constexpr int CPR = BK / 8;
    __shared__ __align__(16) bf16_t As[BM * BK];
    __shared__ __align__(16) bf16_t Bs[BN * BK];
    const int tid = threadIdx.x;
    const int lane = tid & 63;
    const int wr = (tid >> 7) & 1;
    const int wc = (tid >> 6) & 1;

    A += (size_t)tm * lda;
    B += (size_t)tn * ldb;

    floatx4 acc[FM][FN] = {};

    for (int k0 = 0; k0 < K; k0 += BK) {
#pragma unroll
        for (int i = 0; i < (BM * CPR) / 256; ++i) {
            int c = i * 256 + tid;
            int m = c / CPR, kc = c % CPR;
            gld_lds16(A + (size_t)m * lda + k0 + kc * 8, As + c * 8);
        }
#pragma unroll
        for (int i = 0; i < (BN * CPR) / 256; ++i) {
            int c = i * 256 + tid;
            int m = c / CPR, kc = c % CPR;
            gld_lds16(B + (size_t)m * ldb + k0 + kc * 8, Bs + c * 8);
        }
        __syncthreads();

#pragma unroll
        for (int kk = 0; kk < BK; kk += 32) {
            bf16x8 aF[FM], bF[FN];
#pragma unroll
            for (int fm = 0; fm < FM; ++fm)
                aF[fm] = *(const bf16x8*)(As + (wr * WM + fm * 16 + (lane & 15)) * BK +
                                          kk + (lane >> 4) * 8);
#pragma unroll
            for (int fn = 0; fn < FN; ++fn)
                bF[fn] = *(const bf16x8*)(Bs + (wc * WN + fn * 16 + (lane & 15)) * BK +
                                          kk + (lane >> 4) * 8);
#pragma unroll
            for (int fm = 0; fm < FM; ++fm)
#pragma unroll
                for (int fn = 0; fn < FN; ++fn)
                    acc[fm][fn] = __builtin_amdgcn_mfma_f32_16x16x32_bf16(
                        aF[fm], bF[fn], acc[fm][fn], 0, 0, 0);
        }
        __syncthreads();
    }

    const int cr4 = (lane >> 4) * 4;
    const int cn = lane & 15;
#pragma unroll
    for (int fm = 0; fm < FM; ++fm)
#pragma unroll
        for (int fn = 0; fn < FN; ++fn)
#pragma unroll
            for (int r = 0; r < 4; ++r) {
                int m = tm + wr * WM + fm * 16 + cr4 + r;
                int n = tn + wc * WN + fn * 16 + cn;
                size_t idx = TRANS_OUT ? ((size_t)n * ldc + m)
                                       : ((size_t)m * ldc + n);
                if (OUT_MODE == 0)
                    ((float*)Cp)[idx] = acc[fm][fn][r];
                else
                    ((unsigned short*)Cp)[idx] = f2bf(acc[fm][fn][r]);
            }
}

// ---- k_xtx: Gp[chunk][b][i][j] = sum_{l in chunk} xT[b][i][l]*xT[b][j][l]
// 128x64 tiles, split-K over L=4096 in 4 private chunks -> 256 blocks,
// plain stores (no atomics, no zero-init).
__global__ __launch_bounds__(256) void k_xtx(const bf16_t* xT, float* Gp) {
    const int t = blockIdx.x;          // 0..31 : (it 0..3) x (jt 0..7)
    const int chunk = blockIdx.y;      // 0..3
    const int b = blockIdx.z;
    const int i0 = (t >> 3) * 128, j0 = (t & 7) * 64;
    const bf16_t* Xb = xT + (size_t)b * DIN * LDIM + (size_t)chunk * 1024;
    float* Gc = Gp + ((size_t)chunk * BDIM + b) * DIN * DIN;
    gemm_core<128, 64, 64, false, 0>(Xb, Xb, Gc, 1024, LDIM, LDIM, DIN, i0, j0);
}

// ---- k_gvm: per (jt, h, b):
//   T2[dk][jl] = sum_i WkT[h][dk][i] * G[b][j0+jl][i]   (G = sum of 4 partials)
//   M32[b,h][dk][v] += sum_jl T2[dk][jl] * WvT[h][v][j0+jl]
__global__ __launch_bounds__(256) void k_gvm(const bf16_t* WkT, const bf16_t* WvT,
                                             const float* Gp, float* M32) {
    const int jt = blockIdx.x, h = blockIdx.y, b = blockIdx.z;
    const int j0 = jt * 64;
    __shared__ __align__(16) bf16_t As[64 * 64];
    __shared__ __align__(16) bf16_t Bs[64 * 64];
    __shared__ __align__(16) bf16_t Vs[64 * 64];
    __shared__ __align__(16) bf16_t T2s[64 * 64];
    const int tid = threadIdx.x;
    const int lane = tid & 63;
    const int wr = (tid >> 7) & 1, wc = (tid >> 6) & 1;
    const int cr4 = (lane >> 4) * 4, cn = lane & 15;

    const bf16_t* A = WkT + (size_t)h * DK * DIN;
    constexpr size_t GSTRIDE = (size_t)BDIM * DIN * DIN;

    floatx4 acc[2][2] = {};
    for (int k0 = 0; k0 < DIN; k0 += 64) {
#pragma unroll
        for (int i = 0; i < 2; ++i) {
            int c = i * 256 + tid, m = c >> 3, kc = c & 7;
            gld_lds16(A + (size_t)m * DIN + k0 + kc * 8, As + c * 8);
        }
#pragma unroll
        for (int i = 0; i < 2; ++i) {
            int c = i * 256 + tid, n = c >> 3, kc = c & 7;
            const float* g0 = Gp + ((size_t)b * DIN + j0 + n) * DIN + k0 + kc * 8;
            float4 s0 = *(const float4*)g0;
            float4 s1 = *(const float4*)(g0 + 4);
#pragma unroll
            for (int ch = 1; ch < NCHUNK; ++ch) {
                const float* gc = g0 + (size_t)ch * GSTRIDE;
                float4 t0 = *(const float4*)gc;
                float4 t1 = *(const float4*)(gc + 4);
                s0.x += t0.x; s0.y += t0.y; s0.z += t0.z; s0.w += t0.w;
                s1.x += t1.x; s1.y += t1.y; s1.z += t1.z; s1.w += t1.w;
            }
            unsigned short o[8] = {f2bf(s0.x), f2bf(s0.y), f2bf(s0.z), f2bf(s0.w),
                                   f2bf(s1.x), f2bf(s1.y), f2bf(s1.z), f2bf(s1.w)};
            *(uint4*)((unsigned short*)Bs + (size_t)c * 8) = *(const uint4*)o;
        }
        __syncthreads();
#pragma unroll
        for (int kk = 0; kk < 64; kk += 32) {
            bf16x8 aF[2], bF[2];
#pragma unroll
            for (int f = 0; f < 2; ++f) {
                aF[f] = *(const bf16x8*)(As + (wr * 32 + f * 16 + cn) * 64 + kk +
                                         (lane >> 4) * 8);
                bF[f] = *(const bf16x8*)(Bs + (wc * 32 + f * 16 + cn) * 64 + kk +
                                         (lane >> 4) * 8);
            }
#pragma unroll
            for (int fm = 0; fm < 2; ++fm)
#pragma unroll
                for (int fn = 0; fn < 2; ++fn)
                    acc[fm][fn] = __builtin_amdgcn_mfma_f32_16x16x32_bf16(
                        aF[fm], bF[fn], acc[fm][fn], 0, 0, 0);
        }
        __syncthreads();
    }

    // T2 tile -> LDS (bf16), stage Wv j-slice
#pragma unroll
    for (int fm = 0; fm < 2; ++fm)
#pragma unroll
        for (int fn = 0; fn < 2; ++fn)
#pragma unroll
            for (int r = 0; r < 4; ++r) {
                int m = wr * 32 + fm * 16 + cr4 + r;   // dk
                int n = wc * 32 + fn * 16 + cn;        // j local
                ((unsigned short*)T2s)[m * 64 + n] = f2bf(acc[fm][fn][r]);
            }
#pragma unroll
    for (int i = 0; i < 2; ++i) {
        int c = i * 256 + tid, v = c >> 3, kc = c & 7;
        gld_lds16(WvT + ((size_t)h * DV + v) * DIN + j0 + kc * 8, Vs + c * 8);
    }
    __syncthreads();

    floatx4 mm[2][2] = {};
#pragma unroll
    for (int kk = 0; kk < 64; kk += 32) {
        bf16x8 aF[2], bF[2];
#pragma unroll
        for (int f = 0; f < 2; ++f) {
            aF[f] = *(const bf16x8*)(T2s + (wr * 32 + f * 16 + cn) * 64 + kk +
                                     (lane >> 4) * 8);
            bF[f] = *(const bf16x8*)(Vs + (wc * 32 + f * 16 + cn) * 64 + kk +
                                     (lane >> 4) * 8);
        }
#pragma unroll
        for (int fm = 0; fm < 2; ++fm)
#pragma unroll
            for (int fn = 0; fn < 2; ++fn)
                mm[fm][fn] = __builtin_amdgcn_mfma_f32_16x16x32_bf16(
                    aF[fm], bF[fn], mm[fm][fn], 0, 0, 0);
    }
    float* Mh = M32 + ((size_t)(b * HDIM + h)) * (DK * DV);
#pragma unroll
    for (int fm = 0; fm < 2; ++fm)
#pragma unroll
        for (int fn = 0; fn < 2; ++fn)
#pragma unroll
            for (int r = 0; r < 4; ++r) {
                int dk = wr * 32 + fm * 16 + cr4 + r;
                int v = wc * 32 + fn * 16 + cn;
                atomicAdd(&Mh[dk * 64 + v], mm[fm][fn][r]);
            }
}

// ---- k_tail: CT[b][o][i] = sum_h sum_dk PT[h][o][dk] * Wq[h][i][dk]
//      where PT[h][o][dk] = sum_v WoT[h][o][v] * M[b,h][dk][v]
__global__ __launch_bounds__(256) void k_tail(const bf16_t* WqC, const bf16_t* WoT,
                                              const float* M32, unsigned short* CT) {
    int i0 = blockIdx.x * 64, o0 = blockIdx.y * 64, b = blockIdx.z;
    __shared__ __align__(16) bf16_t Aq[64 * 64];
    __shared__ __align__(16) bf16_t Ws[64 * 64];
    __shared__ __align__(16) bf16_t Msh[64 * 64];
    __shared__ __align__(16) bf16_t PTs[64 * 64];
    const int tid = threadIdx.x;
    const int lane = tid & 63;
    const int wr = (tid >> 7) & 1, wc = (tid >> 6) & 1;
    const int cr4 = (lane >> 4) * 4, cn = lane & 15;

    floatx4 acc[2][2] = {};

    for (int h = 0; h < HDIM; ++h) {
#pragma unroll
        for (int i = 0; i < 2; ++i) {
            int c = i * 256 + tid, m = c >> 3, kc = c & 7;
            gld_lds16(WqC + (size_t)(i0 + m) * DIN + h * 64 + kc * 8, Aq + c * 8);
            gld_lds16(WoT + ((size_t)h * DOUT + o0 + m) * DV + kc * 8, Ws + c * 8);
        }
        const float* Mh = M32 + ((size_t)(b * HDIM + h)) * (DK * DV);
#pragma unroll
        for (int i = 0; i < 4; ++i) {
            int idx = (i * 256 + tid) * 4;
            float4 v = *(const float4*)(Mh + idx);
            *(ushort4*)((unsigned short*)Msh + idx) =
                make_ushort4(f2bf(v.x), f2bf(v.y), f2bf(v.z), f2bf(v.w));
        }
        __syncthreads();

        floatx4 pt[2][2] = {};
#pragma unroll
        for (int kk = 0; kk < 64; kk += 32) {
            bf16x8 aF[2], bF[2];
#pragma unroll
            for (int f = 0; f < 2; ++f) {
                aF[f] = *(const bf16x8*)(Ws + (wr * 32 + f * 16 + cn) * 64 + kk +
                                         (lane >> 4) * 8);
                bF[f] = *(const bf16x8*)(Msh + (wc * 32 + f * 16 + cn) * 64 + kk +
                                         (lane >> 4) * 8);
            }
#pragma unroll
            for (int fm = 0; fm < 2; ++fm)
#pragma unroll
                for (int fn = 0; fn < 2; ++fn)
                    pt[fm][fn] = __builtin_amdgcn_mfma_f32_16x16x32_bf16(
                        aF[fm], bF[fn], pt[fm][fn], 0, 0, 0);
        }
#pragma unroll
        for (int fm = 0; fm < 2; ++fm)
#pragma unroll
            for (int fn = 0; fn < 2; ++fn)
#pragma unroll
                for (int r = 0; r < 4; ++r) {
                    int m = wr * 32 + fm * 16 + cr4 + r;
                    int n = wc * 32 + fn * 16 + cn;
                    ((unsigned short*)PTs)[m * 64 + n] = f2bf(pt[fm][fn][r]);
                }
        __syncthreads();

#pragma unroll
        for (int kk = 0; kk < 64; kk += 32) {
            bf16x8 aF[2], bF[2];
#pragma unroll
            for (int f = 0; f < 2; ++f) {
                aF[f] = *(const bf16x8*)(PTs + (wr * 32 + f * 16 + cn) * 64 + kk +
                                         (lane >> 4) * 8);
                bF[f] = *(const bf16x8*)(Aq + (wc * 32 + f * 16 + cn) * 64 + kk +
                                         (lane >> 4) * 8);
            }
#pragma unroll
            for (int fm = 0; fm < 2; ++fm)
#pragma unroll
                for (int fn = 0; fn < 2; ++fn)
                    acc[fm][fn] = __builtin_amdgcn_mfma_f32_16x16x32_bf16(
                        aF[fm], bF[fn], acc[fm][fn], 0, 0, 0);
        }
        __syncthreads();
    }

    unsigned short* CTb = CT + (size_t)b * DIN * DOUT;
#pragma unroll
    for (int fm = 0; fm < 2; ++fm)
#pragma unroll
        for (int fn = 0; fn < 2; ++fn)
#pragma unroll
            for (int r = 0; r < 4; ++r) {
                int m = wr * 32 + fm * 16 + cr4 + r;
                int n = wc * 32 + fn * 16 + cn;
                CTb[(size_t)(o0 + m) * DIN + i0 + n] = f2bf(acc[fm][fn][r]);
            }
}

// ---- out[b] = x16[b] @ C[b], fp32 out, 64x128 tiles ----
__global__ __launch_bounds__(256) void k_out(const bf16_t* x16, const bf16_t* CT,
                                             float* out) {
    int b = blockIdx.z;
    gemm_core<64, 128, 64, false, 0>(x16 + (size_t)b * LDIM * DIN,
                                     CT + (size_t)b * DIN * DOUT,
                                     out + (size_t)b * LDIM * DOUT, DIN, DIN,
                                     DIN, DOUT, blockIdx.x * 64,
                                     blockIdx.y * 128);
}

// ---------------- prep: fused x convert+transpose, weights, zero M ----
// bids: [0,1024) x -> xb16 + xT16 (64x64 tiles) | [1024,1280) weights |
//       [1280,1288) zero M32
__global__ __launch_bounds__(256) void k_prep4(
    const float* x, const float* Wq, const float* Wk, const float* Wv,
    const float* Wo, unsigned short* xb, unsigned short* xT,
    unsigned short* WqC, unsigned short* WkT, unsigned short* WvT,
    unsigned short* WoT, float* M32) {
    __shared__ unsigned short T[64][65];
    int tr = threadIdx.x >> 4, tc4 = (threadIdx.x & 15) * 4;
    int bid = blockIdx.x;
    if (bid < 1024) {  // x tile -> xb16 (row) + xT16 (transposed)
        int b = bid >> 9;
        int q = bid & 511;
        int lt = q >> 3, it = q & 7;
        const float* src = x + (size_t)b * LDIM * DIN + (size_t)lt * 64 * DIN +
                           (size_t)it * 64;
        unsigned short* d0 = xb + (size_t)b * LDIM * DIN + (size_t)lt * 64 * DIN +
                             (size_t)it * 64;
        unsigned short* d1 = xT + (size_t)b * DIN * LDIM + (size_t)it * 64 * LDIM +
                             (size_t)lt * 64;
#pragma unroll
        for (int p = 0; p < 4; ++p) {
            int r = p * 16 + tr;
            float4 v = *(const float4*)(src + (size_t)r * DIN + tc4);
            ushort4 u = make_ushort4(f2bf(v.x), f2bf(v.y), f2bf(v.z), f2bf(v.w));
            *(ushort4*)(d0 + (size_t)r * DIN + tc4) = u;
            T[r][tc4 + 0] = u.x; T[r][tc4 + 1] = u.y;
            T[r][tc4 + 2] = u.z; T[r][tc4 + 3] = u.w;
        }
        __syncthreads();
#pragma unroll
        for (int p = 0; p < 4; ++p) {
            int c = p * 16 + tr;
            ushort4 u = make_ushort4(T[tc4 + 0][c], T[tc4 + 1][c], T[tc4 + 2][c],
                                     T[tc4 + 3][c]);
            *(ushort4*)(d1 + (size_t)c * LDIM + tc4) = u;
        }
        return;
    }
    if (bid >= 1280) {  // zero M32 (2 x 8 x 64 x 64 fp32 = 65536 f32)
        size_t g = ((size_t)(bid - 1280) * 256 + threadIdx.x) * 32;
        float4 z4 = make_float4(0.f, 0.f, 0.f, 0.f);
#pragma unroll
        for (int q = 0; q < 8; ++q) *(float4*)(M32 + g + q * 4) = z4;
        return;
    }
    int p_ = bid - 1024;
    int t = p_ & 7, job = (p_ >> 3) & 3, h = p_ >> 5;
    if (job == 0) {  // Wq[h] -> WqC (i-major, head-interleaved columns)
        const float* src = Wq + (size_t)h * DIN * DK;
#pragma unroll
        for (int p = 0; p < 4; ++p) {
            int i = t * 64 + p * 16 + tr;
            float4 v = *(const float4*)(src + (size_t)i * DK + tc4);
            *(ushort4*)(WqC + (size_t)i * (HDIM * DK) + h * DK + tc4) =
                make_ushort4(f2bf(v.x), f2bf(v.y), f2bf(v.z), f2bf(v.w));
        }
        return;
    }
    const float* src;
    unsigned short* dst;
    int rows, cols, r0, c0;
    if (job == 1) {  // Wk[h] (512x64) -> WkT[h] (64x512)
        src = Wk + (size_t)h * DIN * DK;
        dst = WkT + (size_t)h * DK * DIN;
        rows = DIN; cols = DK; r0 = t * 64; c0 = 0;
    } else if (job == 2) {  // Wv[h] (512x64) -> WvT[h] (64x512)
        src = Wv + (size_t)h * DIN * DV;
        dst = WvT + (size_t)h * DV * DIN;
        rows = DIN; cols = DV; r0 = t * 64; c0 = 0;
    } else {  // Wo[h] (64x512) -> WoT[h] (512x64)
        src = Wo + (size_t)h * DV * DOUT;
        dst = WoT + (size_t)h * DOUT * DV;
        rows = DV; cols = DOUT; r0 = 0; c0 = t * 64;
    }
#pragma unroll
    for (int p = 0; p < 4; ++p) {
        int r = p * 16 + tr;
        float4 v = *(const float4*)(src + (size_t)(r0 + r) * cols + c0 + tc4);
        T[r][tc4 + 0] = f2bf(v.x); T[r][tc4 + 1] = f2bf(v.y);
        T[r][tc4 + 2] = f2bf(v.z); T[r][tc4 + 3] = f2bf(v.w);
    }
    __syncthreads();
#pragma unroll
    for (int p = 0; p < 4; ++p) {
        int c = p * 16 + tr;
        ushort4 u = make_ushort4(T[tc4 + 0][c], T[tc4 + 1][c], T[tc4 + 2][c],
                                 T[tc4 + 3][c]);
        *(ushort4*)(dst + (size_t)(c0 + c) * rows + r0 + tc4) = u;
    }
}

extern "C" void kernel_launch(void* const* d_in, const int* in_sizes, int n_in,
                              void* d_out, int out_size, void* d_ws, size_t ws_size,
                              hipStream_t stream) {
    const float* x  = (const float*)d_in[0];
    const float* Wq = (const float*)d_in[1];
    const float* Wk = (const float*)d_in[2];
    const float* Wv = (const float*)d_in[3];
    const float* Wo = (const float*)d_in[4];
    float* out = (float*)d_out;

    unsigned short* w = (unsigned short*)d_ws;
    unsigned short* xb16 = w; w += (size_t)BDIM * LDIM * DIN;   // 8.4 MB
    unsigned short* xT16 = w; w += (size_t)BDIM * DIN * LDIM;   // 8.4 MB
    unsigned short* WqC  = w; w += (size_t)DIN * HDIM * DK;
    unsigned short* WkT  = w; w += (size_t)HDIM * DK * DIN;
    unsigned short* WvT  = w; w += (size_t)HDIM * DV * DIN;
    unsigned short* WoT  = w; w += (size_t)HDIM * DOUT * DV;
    unsigned short* CT   = w; w += (size_t)BDIM * DIN * DOUT;
    float* Gp = (float*)(((uintptr_t)w + 255) & ~(uintptr_t)255);  // 4x2x512x512
    float* M32 = Gp + (size_t)NCHUNK * BDIM * DIN * DIN;           // 2x8x64x64

    k_prep4<<<dim3(1288), 256, 0, stream>>>(x, Wq, Wk, Wv, Wo, xb16, xT16,
                                            WqC, WkT, WvT, WoT, M32);
    k_xtx<<<dim3(32, NCHUNK, BDIM), 256, 0, stream>>>((const bf16_t*)xT16, Gp);
    k_gvm<<<dim3(8, HDIM, BDIM), 256, 0, stream>>>((const bf16_t*)WkT,
                                                   (const bf16_t*)WvT, Gp, M32);
    k_tail<<<dim3(8, 8, BDIM), 256, 0, stream>>>((const bf16_t*)WqC,
                                                 (const bf16_t*)WoT, M32, CT);
    k_out<<<dim3(LDIM / 64, DOUT / 128, BDIM), 256, 0, stream>>>(
        (const bf16_t*)xb16, (const bf16_t*)CT, out);
}